// Round 1
// baseline (532.346 us; speedup 1.0000x reference)
//
#include <hip/hip_runtime.h>

#define IN_F 256
#define OUT_F 64
#define BKT_BITS 9           // 512 nodes per scan block
#define CHUNK 8192           // edges per block for hist pass

typedef __attribute__((ext_vector_type(8))) short short8;    // 8 bf16 (4 VGPRs) — MFMA A/B frag
typedef __attribute__((ext_vector_type(4))) float floatx4;   // MFMA C/D frag + vec4 loads

static __device__ __forceinline__ short f2bf_rne(float f) {
    unsigned u = __float_as_uint(f);
    unsigned r = (u + 0x7fffu + ((u >> 16) & 1u)) >> 16;  // round-nearest-even
    return (short)r;
}
static __device__ __forceinline__ float bf2f(short s) {
    return __uint_as_float(((unsigned)(unsigned short)s) << 16);
}

// ---------------- zero per-node counts + per-bucket counts ----------------
__global__ void zero_kernel(int* __restrict__ cnt, int* __restrict__ bcnt, int N) {
    int i = blockIdx.x * blockDim.x + threadIdx.x;
    if (i < N) cnt[i] = 0;
    if (i < 256) bcnt[i] = 0;
}

// ---------------- CSR build pass 1: per-node histogram (global atomics, L2-resident)
// plus per-bucket (512-node) totals via block-local LDS hist -> 1 global atomic each.
__global__ __launch_bounds__(256) void hist_kernel(const int* __restrict__ dst,
                                                   int* __restrict__ cnt,
                                                   int* __restrict__ bcnt, int E, int nbkt) {
    __shared__ int h[256];
    int t = threadIdx.x;
    h[t] = 0;
    __syncthreads();
    int base = blockIdx.x * CHUNK;
#pragma unroll
    for (int j = 0; j < CHUNK / 256; ++j) {
        int e = base + j * 256 + t;
        if (e < E) {
            int d = __builtin_nontemporal_load(dst + e);
            atomicAdd(&cnt[d], 1);          // 400KB array -> stays in L2
            atomicAdd(&h[d >> BKT_BITS], 1);
        }
    }
    __syncthreads();
    if (t < nbkt && h[t]) atomicAdd(&bcnt[t], h[t]);
}

// ---------------- CSR build pass 2: fused scan. Block b: bucket-base = sum(bcnt[0..b-1])
// (in-block reduce, no serial kernel, no cross-block dep), then 512-node exclusive scan.
// Writes offs[] and cursor[] (cursor = working copy consumed by place_kernel).
__global__ __launch_bounds__(256) void scan_kernel(const int* __restrict__ cnt,
                                                   const int* __restrict__ bcnt,
                                                   int* __restrict__ offs,
                                                   int* __restrict__ cursor, int N, int E) {
    __shared__ int ssum[256];
    __shared__ int sbase;
    int t = threadIdx.x;
    int b = blockIdx.x;
    // sum of bucket totals before this bucket (b <= 255 by construction)
    ssum[t] = (t < b) ? bcnt[t] : 0;
    __syncthreads();
    for (int off = 128; off > 0; off >>= 1) {
        if (t < off) ssum[t] += ssum[t + off];
        __syncthreads();
    }
    if (t == 0) sbase = ssum[0];
    __syncthreads();
    int base_b = sbase;
    // exclusive scan of this bucket's 512 per-node counts: thread t owns 2t, 2t+1
    int n0 = (b << BKT_BITS) + 2 * t;
    int a0 = (n0 < N) ? cnt[n0] : 0;
    int a1 = (n0 + 1 < N) ? cnt[n0 + 1] : 0;
    ssum[t] = a0 + a1;
    __syncthreads();
    for (int off = 1; off < 256; off <<= 1) {
        int v = (t >= off) ? ssum[t - off] : 0;
        __syncthreads();
        ssum[t] += v;
        __syncthreads();
    }
    int base = base_b + (t > 0 ? ssum[t - 1] : 0);
    if (n0 < N)     { offs[n0] = base;          cursor[n0] = base; }
    if (n0 + 1 < N) { offs[n0 + 1] = base + a0; cursor[n0 + 1] = base + a0; }
    if (b == 0 && t == 0) offs[N] = E;
}

// ---------------- CSR build pass 3: place edges directly into final CSR slots.
// edges[] is 12.8MB -> fits in aggregate L2 (per-XCD slice ~1.6MB < 4MB): random
// 8B writes merge in-cache, no HBM write amplification. 1 edge per thread.
__global__ __launch_bounds__(256) void place_kernel(const int* __restrict__ src,
                                                    const int* __restrict__ dst,
                                                    const float* __restrict__ w,
                                                    int* __restrict__ cursor,
                                                    int2* __restrict__ edges, int E) {
    int e = blockIdx.x * blockDim.x + threadIdx.x;
    if (e >= E) return;
    int d = __builtin_nontemporal_load(dst + e);
    int s = __builtin_nontemporal_load(src + e);
    float ww = __builtin_nontemporal_load(w + e);
    int pos = atomicAdd(&cursor[d], 1);
    edges[pos] = make_int2(s, __float_as_int(ww));
}

// ---------------- W -> bf16 hi/lo MFMA B-fragments ----------------
__global__ void wfrag_kernel(const float* __restrict__ W,
                             short* __restrict__ bh, short* __restrict__ bl) {
    int t = blockIdx.x * blockDim.x + threadIdx.x;
    if (t >= 32 * 64) return;
    int combo = t >> 6;
    int lane = t & 63;
    int s = combo >> 2;
    int tO = combo & 3;
    int n = 16 * tO + (lane & 15);
    int k0 = 32 * s + (lane >> 4) * 8;
    const float* src = W + (size_t)n * IN_F + k0;
    short* dh = bh + (size_t)t * 8;
    short* dl = bl + (size_t)t * 8;
#pragma unroll
    for (int j = 0; j < 8; ++j) {
        float v = src[j];
        short h = f2bf_rne(v);
        dh[j] = h;
        dl[j] = f2bf_rne(v - bf2f(h));
    }
}

// ---------------- GEMM via MFMA bf16x3 ----------------
__global__ __launch_bounds__(256) void gemm_kernel(const float* __restrict__ x,
                                                   const short8* __restrict__ bh,
                                                   const short8* __restrict__ bl,
                                                   const float* __restrict__ b,
                                                   float* __restrict__ out, int N) {
    int lane = threadIdx.x & 63;
    int wid = threadIdx.x >> 6;
    int node0 = blockIdx.x * 64 + wid * 16;
    if (node0 >= N) return;
    if (node0 + 16 > N) node0 = N - 16;
    int m = lane & 15;
    int q = lane >> 4;

    // x is a pure 102MB stream with zero reuse: nontemporal to keep L2 for W-frags/out
    const floatx4* xr = (const floatx4*)(x + (size_t)(node0 + m) * IN_F) + q * 2;

    floatx4 acc[4];
#pragma unroll
    for (int tO = 0; tO < 4; ++tO) acc[tO] = (floatx4){0.f, 0.f, 0.f, 0.f};

#pragma unroll
    for (int s = 0; s < 8; ++s) {
        floatx4 v0 = __builtin_nontemporal_load(xr + s * 8);
        floatx4 v1 = __builtin_nontemporal_load(xr + s * 8 + 1);
        float vv[8] = {v0[0], v0[1], v0[2], v0[3], v1[0], v1[1], v1[2], v1[3]};
        short8 ah, al;
#pragma unroll
        for (int j = 0; j < 8; ++j) {
            short h = f2bf_rne(vv[j]);
            ah[j] = h;
            al[j] = f2bf_rne(vv[j] - bf2f(h));
        }
#pragma unroll
        for (int tO = 0; tO < 4; ++tO) {
            short8 wh = bh[(s * 4 + tO) * 64 + lane];
            short8 wl = bl[(s * 4 + tO) * 64 + lane];
            acc[tO] = __builtin_amdgcn_mfma_f32_16x16x32_bf16(ah, wh, acc[tO], 0, 0, 0);
            acc[tO] = __builtin_amdgcn_mfma_f32_16x16x32_bf16(al, wh, acc[tO], 0, 0, 0);
            acc[tO] = __builtin_amdgcn_mfma_f32_16x16x32_bf16(ah, wl, acc[tO], 0, 0, 0);
        }
    }

#pragma unroll
    for (int tO = 0; tO < 4; ++tO) {
        float bias = b[16 * tO + m];
#pragma unroll
        for (int r = 0; r < 4; ++r) {
            out[(size_t)(node0 + q * 4 + r) * OUT_F + 16 * tO + m] = acc[tO][r] + bias;
        }
    }
}

// ---------------- SpMM (CSR gather): out[n][f] = sum_e w[e]*in[src[e]][f] ----------------
// L2 policy: edge stream (zero intra-hop reuse) and out stores (consumed next kernel,
// L3 holds them) are nontemporal; L2 capacity reserved for the 16x-reused gather rows.
__global__ __launch_bounds__(256) void spmm_kernel(const int* __restrict__ offs,
                                                   const int2* __restrict__ edges,
                                                   const float* __restrict__ in,
                                                   float* __restrict__ out, int N) {
    int gid = blockIdx.x * blockDim.x + threadIdx.x;
    int node = __builtin_amdgcn_readfirstlane(gid >> 6);
    int lane = threadIdx.x & 63;
    if (node >= N) return;
    int beg = offs[node];
    int end = offs[node + 1];
    const long long* ep = (const long long*)edges;
    float acc = 0.f;
    int e = beg;
    for (; e + 8 <= end; e += 8) {
        long long L[8];
        float v[8];
#pragma unroll
        for (int j = 0; j < 8; ++j) L[j] = __builtin_nontemporal_load(ep + e + j);
#pragma unroll
        for (int j = 0; j < 8; ++j) v[j] = in[(size_t)(int)L[j] * OUT_F + lane];
#pragma unroll
        for (int j = 0; j < 8; ++j) acc = fmaf(__int_as_float((int)(L[j] >> 32)), v[j], acc);
    }
    for (; e < end; ++e) {
        long long L = __builtin_nontemporal_load(ep + e);
        acc = fmaf(__int_as_float((int)(L >> 32)), in[(size_t)(int)L * OUT_F + lane], acc);
    }
    __builtin_nontemporal_store(acc, out + (size_t)node * OUT_F + lane);
}

// ---------------- launch ----------------
extern "C" void kernel_launch(void* const* d_in, const int* in_sizes, int n_in,
                              void* d_out, int out_size, void* d_ws, size_t ws_size,
                              hipStream_t stream) {
    const float* x = (const float*)d_in[0];
    const float* W = (const float*)d_in[1];
    const float* b = (const float*)d_in[2];
    const int* esrc = (const int*)d_in[3];
    const int* edst = (const int*)d_in[4];
    const float* ew = (const float*)d_in[5];
    float* out = (float*)d_out;

    int N = in_sizes[0] / IN_F;
    int E = in_sizes[3];
    int nbkt = (N + 511) >> BKT_BITS;   // 196 for N=100000 (must be <= 256)

    char* ws = (char*)d_ws;
    size_t off = 0;
    float* buf0 = (float*)(ws + off);    off += (size_t)N * OUT_F * sizeof(float);
    int2* edges = (int2*)(ws + off);     off += (size_t)(E + 8) * sizeof(int2);
    int* offs = (int*)(ws + off);        off += (size_t)(N + 1) * sizeof(int);
    int* cursor = (int*)(ws + off);      off += (size_t)N * sizeof(int);
    int* cnt = (int*)(ws + off);         off += (size_t)N * sizeof(int);
    int* bcnt = (int*)(ws + off);        off += 256 * sizeof(int);
    short* bh = (short*)(ws + off);      off += 32 * 64 * 8 * sizeof(short);
    short* bl = (short*)(ws + off);      off += 32 * 64 * 8 * sizeof(short);
    (void)ws_size; (void)n_in; (void)out_size;

    // CSR build: direct (no binned intermediate)
    zero_kernel<<<(N + 255) / 256, 256, 0, stream>>>(cnt, bcnt, N);
    hist_kernel<<<(E + CHUNK - 1) / CHUNK, 256, 0, stream>>>(edst, cnt, bcnt, E, nbkt);
    scan_kernel<<<nbkt, 256, 0, stream>>>(cnt, bcnt, offs, cursor, N, E);
    place_kernel<<<(E + 255) / 256, 256, 0, stream>>>(esrc, edst, ew, cursor, edges, E);

    // projection
    wfrag_kernel<<<8, 256, 0, stream>>>(W, bh, bl);
    gemm_kernel<<<(N + 63) / 64, 256, 0, stream>>>(x, (const short8*)bh, (const short8*)bl,
                                                   b, buf0, N);

    // 3 hops
    int spmm_blocks = (N * 64 + 255) / 256;
    spmm_kernel<<<spmm_blocks, 256, 0, stream>>>(offs, edges, buf0, out, N);
    spmm_kernel<<<spmm_blocks, 256, 0, stream>>>(offs, edges, out, buf0, N);
    spmm_kernel<<<spmm_blocks, 256, 0, stream>>>(offs, edges, buf0, out, N);
}

// Round 2
// 449.096 us; speedup vs baseline: 1.1854x; 1.1854x over previous
//
#include <hip/hip_runtime.h>

#define IN_F 256
#define OUT_F 64
#define BKT_BITS 9           // 512 nodes per bucket
#define BKT_NODES 512
#define BKT_CAP 12288        // fixed bucket capacity; mean 8192, sigma ~90 -> huge margin
#define CHUNK 8192           // edges per block for binning pass
#define SRC_BITS 18          // N < 262144
#define SRC_MASK 0x3FFFF

typedef __attribute__((ext_vector_type(8))) short short8;    // 8 bf16 (4 VGPRs) — MFMA A/B frag
typedef __attribute__((ext_vector_type(4))) float floatx4;   // MFMA C/D frag

static __device__ __forceinline__ short f2bf_rne(float f) {
    unsigned u = __float_as_uint(f);
    unsigned r = (u + 0x7fffu + ((u >> 16) & 1u)) >> 16;  // round-nearest-even
    return (short)r;
}
static __device__ __forceinline__ float bf2f(short s) {
    return __uint_as_float(((unsigned)(unsigned short)s) << 16);
}

// ---------------- utility ----------------
__global__ void zero_kernel(int* __restrict__ p, int n) {
    int i = blockIdx.x * blockDim.x + threadIdx.x;
    if (i < n) p[i] = 0;
}

// ---------------- CSR build, pass 1: bin into fixed-capacity dst-buckets ----------------
// Block-local LDS hist -> one global atomic reservation per (block,bucket) ->
// contiguous ~42-edge runs per region (write amp ~1.2x, all from ONE block/XCD so the
// bucket window merges in that XCD's L2 — this is why direct scatter loses 8x here).
// binned[bkt*BKT_CAP + i].x = (dst_offset_in_bucket << SRC_BITS) | src, .y = w bits.
__global__ __launch_bounds__(256) void bin_kernel(const int* __restrict__ src,
                                                  const int* __restrict__ dst,
                                                  const float* __restrict__ w,
                                                  int* __restrict__ bkt_cnt,
                                                  int2* __restrict__ binned, int E, int nbkt) {
    __shared__ int h[256];
    int t = threadIdx.x;
    h[t] = 0;
    __syncthreads();
    int base = blockIdx.x * CHUNK;
#pragma unroll
    for (int j = 0; j < CHUNK / 256; ++j) {
        int e = base + j * 256 + t;
        if (e < E) atomicAdd(&h[__builtin_nontemporal_load(dst + e) >> BKT_BITS], 1);
    }
    __syncthreads();
    int c = h[t];
    int rbase = 0;
    if (t < nbkt && c) rbase = atomicAdd(&bkt_cnt[t], c);
    __syncthreads();
    h[t] = rbase;  // becomes block-local cursor (offset within bucket region)
    __syncthreads();
#pragma unroll
    for (int j = 0; j < CHUNK / 256; ++j) {
        int e = base + j * 256 + t;
        if (e < E) {
            int d = dst[e];
            int bb = d >> BKT_BITS;
            int pos = atomicAdd(&h[bb], 1);
            binned[(size_t)bb * BKT_CAP + pos] =
                make_int2(((d & (BKT_NODES - 1)) << SRC_BITS) | src[e], __float_as_int(w[e]));
        }
    }
}

// tiny serial exclusive scan over bucket totals -> global edge-array base per bucket
__global__ void bucket_scan_kernel(const int* __restrict__ bkt_cnt, int* __restrict__ bkt_off,
                                   int nbkt) {
    if (blockIdx.x == 0 && threadIdx.x == 0) {
        int run = 0;
        for (int i = 0; i < nbkt; ++i) {
            bkt_off[i] = run;
            run += bkt_cnt[i];
        }
    }
}

// ---------------- CSR build, pass 2 (fused): per-bucket count + scan + offs + place ------
__global__ __launch_bounds__(256) void build_bucket_kernel(const int2* __restrict__ binned,
                                                           const int* __restrict__ bkt_cnt,
                                                           const int* __restrict__ bkt_off,
                                                           int* __restrict__ offs,
                                                           int2* __restrict__ edges,
                                                           int N, int E) {
    __shared__ int h[BKT_NODES];   // per-node counts, then cursors
    __shared__ int ssum[256];
    int t = threadIdx.x;
    int b = blockIdx.x;
    h[t] = 0;
    h[t + 256] = 0;
    __syncthreads();
    int cntb = bkt_cnt[b];
    const int2* bsrc = binned + (size_t)b * BKT_CAP;
    for (int e = t; e < cntb; e += 256) atomicAdd(&h[bsrc[e].x >> SRC_BITS], 1);
    __syncthreads();
    // exclusive scan of 512 counts: thread t owns elements 2t, 2t+1
    int a0 = h[2 * t], a1 = h[2 * t + 1];
    ssum[t] = a0 + a1;
    __syncthreads();
    for (int off = 1; off < 256; off <<= 1) {
        int v = (t >= off) ? ssum[t - off] : 0;
        __syncthreads();
        ssum[t] += v;
        __syncthreads();
    }
    int base = bkt_off[b] + (t > 0 ? ssum[t - 1] : 0);
    int node0 = (b << BKT_BITS) + 2 * t;
    if (node0 < N) offs[node0] = base;
    if (node0 + 1 < N) offs[node0 + 1] = base + a0;
    __syncthreads();  // all reads of h-as-counts done
    h[2 * t] = base;
    h[2 * t + 1] = base + a0;
    __syncthreads();
    for (int e = t; e < cntb; e += 256) {
        int2 v = bsrc[e];
        int pos = atomicAdd(&h[v.x >> SRC_BITS], 1);
        edges[pos] = make_int2(v.x & SRC_MASK, v.y);
    }
    if (b == 0 && t == 0) offs[N] = E;
}

// ---------------- W -> bf16 hi/lo MFMA B-fragments ----------------
__global__ void wfrag_kernel(const float* __restrict__ W,
                             short* __restrict__ bh, short* __restrict__ bl) {
    int t = blockIdx.x * blockDim.x + threadIdx.x;
    if (t >= 32 * 64) return;
    int combo = t >> 6;
    int lane = t & 63;
    int s = combo >> 2;
    int tO = combo & 3;
    int n = 16 * tO + (lane & 15);
    int k0 = 32 * s + (lane >> 4) * 8;
    const float* src = W + (size_t)n * IN_F + k0;
    short* dh = bh + (size_t)t * 8;
    short* dl = bl + (size_t)t * 8;
#pragma unroll
    for (int j = 0; j < 8; ++j) {
        float v = src[j];
        short h = f2bf_rne(v);
        dh[j] = h;
        dl[j] = f2bf_rne(v - bf2f(h));
    }
}

// ---------------- GEMM via MFMA bf16x3 ----------------
__global__ __launch_bounds__(256) void gemm_kernel(const float* __restrict__ x,
                                                   const short8* __restrict__ bh,
                                                   const short8* __restrict__ bl,
                                                   const float* __restrict__ b,
                                                   float* __restrict__ out, int N) {
    int lane = threadIdx.x & 63;
    int wid = threadIdx.x >> 6;
    int node0 = blockIdx.x * 64 + wid * 16;
    if (node0 >= N) return;
    if (node0 + 16 > N) node0 = N - 16;
    int m = lane & 15;
    int q = lane >> 4;

    // x is a pure 102MB stream with zero reuse: nontemporal keeps L2 for everything else
    const floatx4* xr = (const floatx4*)(x + (size_t)(node0 + m) * IN_F) + q * 2;

    floatx4 acc[4];
#pragma unroll
    for (int tO = 0; tO < 4; ++tO) acc[tO] = (floatx4){0.f, 0.f, 0.f, 0.f};

#pragma unroll
    for (int s = 0; s < 8; ++s) {
        floatx4 v0 = __builtin_nontemporal_load(xr + s * 8);
        floatx4 v1 = __builtin_nontemporal_load(xr + s * 8 + 1);
        float vv[8] = {v0[0], v0[1], v0[2], v0[3], v1[0], v1[1], v1[2], v1[3]};
        short8 ah, al;
#pragma unroll
        for (int j = 0; j < 8; ++j) {
            short h = f2bf_rne(vv[j]);
            ah[j] = h;
            al[j] = f2bf_rne(vv[j] - bf2f(h));
        }
#pragma unroll
        for (int tO = 0; tO < 4; ++tO) {
            short8 wh = bh[(s * 4 + tO) * 64 + lane];
            short8 wl = bl[(s * 4 + tO) * 64 + lane];
            acc[tO] = __builtin_amdgcn_mfma_f32_16x16x32_bf16(ah, wh, acc[tO], 0, 0, 0);
            acc[tO] = __builtin_amdgcn_mfma_f32_16x16x32_bf16(al, wh, acc[tO], 0, 0, 0);
            acc[tO] = __builtin_amdgcn_mfma_f32_16x16x32_bf16(ah, wl, acc[tO], 0, 0, 0);
        }
    }

#pragma unroll
    for (int tO = 0; tO < 4; ++tO) {
        float bias = b[16 * tO + m];
#pragma unroll
        for (int r = 0; r < 4; ++r) {
            out[(size_t)(node0 + q * 4 + r) * OUT_F + 16 * tO + m] = acc[tO][r] + bias;
        }
    }
}

// ---------------- SpMM (CSR gather): out[n][f] = sum_e w[e]*in[src[e]][f] ----------------
// L2 policy: edge stream (zero intra-hop reuse) and out stores (consumed next kernel,
// L3 holds them) are nontemporal; L2 capacity reserved for the 16x-reused gather rows.
__global__ __launch_bounds__(256) void spmm_kernel(const int* __restrict__ offs,
                                                   const int2* __restrict__ edges,
                                                   const float* __restrict__ in,
                                                   float* __restrict__ out, int N) {
    int gid = blockIdx.x * blockDim.x + threadIdx.x;
    int node = __builtin_amdgcn_readfirstlane(gid >> 6);
    int lane = threadIdx.x & 63;
    if (node >= N) return;
    int beg = offs[node];
    int end = offs[node + 1];
    const long long* ep = (const long long*)edges;
    float acc = 0.f;
    int e = beg;
    for (; e + 8 <= end; e += 8) {
        long long L[8];
        float v[8];
#pragma unroll
        for (int j = 0; j < 8; ++j) L[j] = __builtin_nontemporal_load(ep + e + j);
#pragma unroll
        for (int j = 0; j < 8; ++j) v[j] = in[(size_t)(int)L[j] * OUT_F + lane];
#pragma unroll
        for (int j = 0; j < 8; ++j) acc = fmaf(__int_as_float((int)(L[j] >> 32)), v[j], acc);
    }
    for (; e < end; ++e) {
        long long L = __builtin_nontemporal_load(ep + e);
        acc = fmaf(__int_as_float((int)(L >> 32)), in[(size_t)(int)L * OUT_F + lane], acc);
    }
    __builtin_nontemporal_store(acc, out + (size_t)node * OUT_F + lane);
}

// ---------------- launch ----------------
extern "C" void kernel_launch(void* const* d_in, const int* in_sizes, int n_in,
                              void* d_out, int out_size, void* d_ws, size_t ws_size,
                              hipStream_t stream) {
    const float* x = (const float*)d_in[0];
    const float* W = (const float*)d_in[1];
    const float* b = (const float*)d_in[2];
    const int* esrc = (const int*)d_in[3];
    const int* edst = (const int*)d_in[4];
    const float* ew = (const float*)d_in[5];
    float* out = (float*)d_out;

    int N = in_sizes[0] / IN_F;
    int E = in_sizes[3];
    int nbkt = (N + BKT_NODES - 1) >> BKT_BITS;   // 196 for N=100000 (must be <= 256)

    char* ws = (char*)d_ws;
    size_t off = 0;
    float* buf0 = (float*)(ws + off);    off += (size_t)N * OUT_F * sizeof(float);
    int2* edges = (int2*)(ws + off);     off += (size_t)(E + 8) * sizeof(int2);
    int* offs = (int*)(ws + off);        off += (size_t)(N + 1) * sizeof(int);
    int* bkt_cnt = (int*)(ws + off);     off += 1024 * sizeof(int);
    int* bkt_off = (int*)(ws + off);     off += 1024 * sizeof(int);
    short* bh = (short*)(ws + off);      off += 32 * 64 * 8 * sizeof(short);
    short* bl = (short*)(ws + off);      off += 32 * 64 * 8 * sizeof(short);
    // binned aliases buf0's region (196*12288*8B = 19.3MB <= 25.6MB): buf0 is only
    // written by gemm, which runs after build_bucket_kernel consumed binned.
    int2* binned = (int2*)buf0;
    (void)ws_size; (void)n_in; (void)out_size;

    int nb_chunk = (E + CHUNK - 1) / CHUNK;

    // CSR build: 4 kernels
    zero_kernel<<<1, 256, 0, stream>>>(bkt_cnt, nbkt);
    bin_kernel<<<nb_chunk, 256, 0, stream>>>(esrc, edst, ew, bkt_cnt, binned, E, nbkt);
    bucket_scan_kernel<<<1, 64, 0, stream>>>(bkt_cnt, bkt_off, nbkt);
    build_bucket_kernel<<<nbkt, 256, 0, stream>>>(binned, bkt_cnt, bkt_off, offs, edges, N, E);

    // projection
    wfrag_kernel<<<8, 256, 0, stream>>>(W, bh, bl);
    gemm_kernel<<<(N + 63) / 64, 256, 0, stream>>>(x, (const short8*)bh, (const short8*)bl,
                                                   b, buf0, N);

    // 3 hops
    int spmm_blocks = (N * 64 + 255) / 256;
    spmm_kernel<<<spmm_blocks, 256, 0, stream>>>(offs, edges, buf0, out, N);
    spmm_kernel<<<spmm_blocks, 256, 0, stream>>>(offs, edges, out, buf0, N);
    spmm_kernel<<<spmm_blocks, 256, 0, stream>>>(offs, edges, buf0, out, N);
}